// Round 1
// baseline (261.877 us; speedup 1.0000x reference)
//
#include <hip/hip_runtime.h>
#include <stdint.h>

#define B_   32
#define CIN  256
#define COUT 512
#define A_   256
#define HW_  4096
#define NT   64

typedef short  short8  __attribute__((ext_vector_type(8)));
typedef float  float4_ __attribute__((ext_vector_type(4)));

__device__ __forceinline__ unsigned short f2bf(float f) {
    unsigned u = __float_as_uint(f);
    u += 0x7FFFu + ((u >> 16) & 1u);   // RNE to bf16
    return (unsigned short)(u >> 16);
}

// Kernel 0: zero P/T, convert Wx -> bf16, compute ggbx[b][a] = g@Wg.T + bg + bx
__global__ __launch_bounds__(256) void prep_kernel(
    const float* __restrict__ g, const float* __restrict__ Wg,
    const float* __restrict__ bg, const float* __restrict__ Wx,
    const float* __restrict__ bx,
    unsigned short* __restrict__ Wxbf, float* __restrict__ ggbx,
    float* __restrict__ P, float* __restrict__ T)
{
    int b = blockIdx.x, t = threadIdx.x;
    int i = b * 256 + t;                       // 0..8191
    P[i] = 0.f; T[i] = 0.f;

    // convert 8 Wx elements per thread (covers 65536)
    const float4* src = (const float4*)(Wx + (size_t)i * 8);
    float4 v0 = src[0], v1 = src[1];
    uint4 pk;
    pk.x = (unsigned)f2bf(v0.x) | ((unsigned)f2bf(v0.y) << 16);
    pk.y = (unsigned)f2bf(v0.z) | ((unsigned)f2bf(v0.w) << 16);
    pk.z = (unsigned)f2bf(v1.x) | ((unsigned)f2bf(v1.y) << 16);
    pk.w = (unsigned)f2bf(v1.z) | ((unsigned)f2bf(v1.w) << 16);
    *(uint4*)(Wxbf + (size_t)i * 8) = pk;

    __shared__ float gl[COUT];
    gl[t]       = g[b * COUT + t];
    gl[t + 256] = g[b * COUT + 256 + t];
    __syncthreads();

    float acc = bg[t] + bx[t];                 // a = t
    const float4* wr = (const float4*)(Wg + (size_t)t * COUT);
    #pragma unroll 4
    for (int co = 0; co < COUT / 4; co++) {
        float4 wv = wr[co];
        float4 gv = *(const float4*)&gl[co * 4];
        acc += wv.x * gv.x + wv.y * gv.y + wv.z * gv.z + wv.w * gv.w;
    }
    ggbx[b * 256 + t] = acc;
}

// Kernel 1: per (b, n-tile of 64): MFMA GEMM + relu + Wf reduce -> raw[b][n],
// plus partial P[b][c] = sum_n x*raw, T[b][c] = sum_n x   (fp32 atomics)
__global__ __launch_bounds__(256, 3) void attn_main(
    const float* __restrict__ x, const unsigned short* __restrict__ Wxbf,
    const float* __restrict__ ggbx, const float* __restrict__ Wf,
    const float* __restrict__ bfs,
    float* __restrict__ P, float* __restrict__ T, float* __restrict__ raw)
{
    // xT: [n=0..63][chunk 0..31][8 bf16], chunk position XOR-swizzled by n&31.
    __shared__ unsigned int xT[NT * 128];      // 32 KB
    __shared__ float att_part[4][NT];
    __shared__ float raw_l[NT];

    int bid = blockIdx.x;
    int b = bid >> 6, nt = bid & 63;
    int t = threadIdx.x, w = t >> 6, lane = t & 63;
    int quad = lane >> 4, l15 = lane & 15;

    const float* xb = x + (size_t)b * CIN * HW_ + nt * NT;

    // ---- stage x tile (fp32 -> bf16, transposed into xT[n][c]) ----
    #pragma unroll
    for (int i = 0; i < 8; i++) {
        int c0 = 8 * (w + 4 * i);              // wave-disjoint chunk rows
        float v[8];
        #pragma unroll
        for (int j = 0; j < 8; j++) v[j] = xb[(size_t)(c0 + j) * HW_ + lane];
        uint4 pk;
        pk.x = (unsigned)f2bf(v[0]) | ((unsigned)f2bf(v[1]) << 16);
        pk.y = (unsigned)f2bf(v[2]) | ((unsigned)f2bf(v[3]) << 16);
        pk.z = (unsigned)f2bf(v[4]) | ((unsigned)f2bf(v[5]) << 16);
        pk.w = (unsigned)f2bf(v[6]) | ((unsigned)f2bf(v[7]) << 16);
        int q = c0 >> 3;
        *(uint4*)&xT[lane * 128 + ((q ^ (lane & 31)) << 2)] = pk;
    }

    // per-wave a-range: a = w*64 + ai*16 + l15
    float ga[4], wfv[4];
    #pragma unroll
    for (int ai = 0; ai < 4; ai++) {
        int a = w * 64 + ai * 16 + l15;
        ga[ai]  = ggbx[b * 256 + a];
        wfv[ai] = Wf[a];
    }
    __syncthreads();

    float4_ acc[4][4];
    #pragma unroll
    for (int mi = 0; mi < 4; mi++)
        #pragma unroll
        for (int ai = 0; ai < 4; ai++)
            acc[mi][ai] = (float4_){0.f, 0.f, 0.f, 0.f};

    // ---- K loop: D[m=n_spatial][n'=a] = xT * Wx^T ----
    for (int k0 = 0; k0 < CIN; k0 += 32) {
        int qk = (k0 >> 3) + quad;
        short8 af[4];
        #pragma unroll
        for (int mi = 0; mi < 4; mi++) {
            int n = mi * 16 + l15;             // A[m=lane&15][k=quad*8+j]
            af[mi] = *(const short8*)&xT[n * 128 + ((qk ^ (n & 31)) << 2)];
        }
        short8 bfr[4];
        #pragma unroll
        for (int ai = 0; ai < 4; ai++) {
            int a = w * 64 + ai * 16 + l15;    // B[k=quad*8+j][n=lane&15]
            bfr[ai] = *(const short8*)(Wxbf + (size_t)a * 256 + k0 + quad * 8);
        }
        #pragma unroll
        for (int mi = 0; mi < 4; mi++)
            #pragma unroll
            for (int ai = 0; ai < 4; ai++)
                acc[mi][ai] = __builtin_amdgcn_mfma_f32_16x16x32_bf16(
                    af[mi], bfr[ai], acc[mi][ai], 0, 0, 0);
    }

    // ---- epilogue: relu(D + gg + bx) * Wf, reduce over a ----
    #pragma unroll
    for (int mi = 0; mi < 4; mi++) {
        float p[4] = {0.f, 0.f, 0.f, 0.f};
        #pragma unroll
        for (int ai = 0; ai < 4; ai++) {
            #pragma unroll
            for (int r = 0; r < 4; r++) {
                float vv = acc[mi][ai][r] + ga[ai];
                vv = fmaxf(vv, 0.f);
                p[r] = fmaf(vv, wfv[ai], p[r]);
            }
        }
        #pragma unroll
        for (int r = 0; r < 4; r++) {
            #pragma unroll
            for (int off = 1; off < 16; off <<= 1)
                p[r] += __shfl_xor(p[r], off, 16);
        }
        if (l15 == 0) {
            #pragma unroll
            for (int r = 0; r < 4; r++)
                att_part[w][mi * 16 + quad * 4 + r] = p[r];
        }
    }
    __syncthreads();

    if (t < NT) {
        float rv = att_part[0][t] + att_part[1][t] + att_part[2][t] + att_part[3][t] + bfs[0];
        raw[b * HW_ + nt * NT + t] = rv;
        raw_l[t] = rv;
    }
    __syncthreads();

    // ---- P/T pass: c = t, read bf16 x back from LDS ----
    float pp = 0.f, tt = 0.f;
    int q = t >> 3, dw = (t & 7) >> 1, hi = t & 1;
    #pragma unroll 8
    for (int n = 0; n < NT; n++) {
        unsigned u = xT[n * 128 + ((q ^ (n & 31)) << 2) + dw];
        unsigned short h = hi ? (unsigned short)(u >> 16) : (unsigned short)(u & 0xFFFFu);
        float xv = __uint_as_float(((unsigned)h) << 16);
        float rv = raw_l[n];
        pp = fmaf(xv, rv, pp);
        tt += xv;
    }
    atomicAdd(&P[b * 256 + t], pp);
    atomicAdd(&T[b * 256 + t], tt);
}

// Kernel 2: per batch: min/sum over raw, write att output and pooled out
__global__ __launch_bounds__(256) void finalize_kernel(
    const float* __restrict__ raw, const float* __restrict__ P,
    const float* __restrict__ T, float* __restrict__ out)
{
    int b = blockIdx.x, t = threadIdx.x;
    const float* r = raw + (size_t)b * HW_;
    float v[16];
    float mn = 3.4e38f, sm = 0.f;
    #pragma unroll
    for (int i = 0; i < 16; i++) {
        v[i] = r[t + 256 * i];
        mn = fminf(mn, v[i]);
        sm += v[i];
    }
    #pragma unroll
    for (int off = 1; off < 64; off <<= 1) {
        mn = fminf(mn, __shfl_xor(mn, off, 64));
        sm += __shfl_xor(sm, off, 64);
    }
    __shared__ float smn[4], ssm[4];
    int w = t >> 6;
    if ((t & 63) == 0) { smn[w] = mn; ssm[w] = sm; }
    __syncthreads();
    mn = fminf(fminf(smn[0], smn[1]), fminf(smn[2], smn[3]));
    sm = (ssm[0] + ssm[1]) + (ssm[2] + ssm[3]);
    float S = sm - 4096.f * mn;                 // sum of (raw - min)
    float inv = 1.f / S;

    float* att = out + B_ * CIN + (size_t)b * HW_;
    #pragma unroll
    for (int i = 0; i < 16; i++) att[t + 256 * i] = (v[i] - mn) * inv;

    int ic = b * 256 + t;
    out[ic] = (P[ic] - mn * T[ic]) * inv;
}

extern "C" void kernel_launch(void* const* d_in, const int* in_sizes, int n_in,
                              void* d_out, int out_size, void* d_ws, size_t ws_size,
                              hipStream_t stream)
{
    const float* x   = (const float*)d_in[0];
    const float* g   = (const float*)d_in[1];
    const float* Wg  = (const float*)d_in[2];
    const float* bg  = (const float*)d_in[3];
    const float* Wx  = (const float*)d_in[4];
    const float* bx  = (const float*)d_in[5];
    const float* Wf  = (const float*)d_in[6];
    const float* bf  = (const float*)d_in[7];
    float* out = (float*)d_out;

    char* wsb = (char*)d_ws;
    unsigned short* Wxbf = (unsigned short*)wsb;          // 128 KB
    float* ggbx = (float*)(wsb + 131072);                 // 32 KB
    float* P    = ggbx + 8192;                            // 32 KB
    float* T    = P + 8192;                               // 32 KB
    float* raw  = T + 8192;                               // 512 KB

    prep_kernel<<<32, 256, 0, stream>>>(g, Wg, bg, Wx, bx, Wxbf, ggbx, P, T);
    attn_main<<<2048, 256, 0, stream>>>(x, Wxbf, ggbx, Wf, bf, P, T, raw);
    finalize_kernel<<<32, 256, 0, stream>>>(raw, P, T, out);
}

// Round 2
// 251.544 us; speedup vs baseline: 1.0411x; 1.0411x over previous
//
#include <hip/hip_runtime.h>
#include <stdint.h>

#define B_   32
#define CIN  256
#define COUT 512
#define A_   256
#define HW_  4096
#define NT   64

typedef short  short8  __attribute__((ext_vector_type(8)));
typedef float  float4_ __attribute__((ext_vector_type(4)));

__device__ __forceinline__ unsigned f2bf(float f) {
    unsigned u = __float_as_uint(f);
    u += 0x7FFFu + ((u >> 16) & 1u);   // RNE to bf16
    return u >> 16;
}
__device__ __forceinline__ float bf2f(unsigned h) {
    return __uint_as_float(h << 16);
}

// Kernel 0: zero P/T, convert Wx -> bf16, compute ggbx[b][a] = g@Wg.T + bg + bx
__global__ __launch_bounds__(256) void prep_kernel(
    const float* __restrict__ g, const float* __restrict__ Wg,
    const float* __restrict__ bg, const float* __restrict__ Wx,
    const float* __restrict__ bx,
    unsigned short* __restrict__ Wxbf, float* __restrict__ ggbx,
    float* __restrict__ P, float* __restrict__ T)
{
    int b = blockIdx.x, t = threadIdx.x;
    int i = b * 256 + t;                       // 0..8191
    P[i] = 0.f; T[i] = 0.f;

    // convert 8 Wx elements per thread (covers 65536)
    const float4* src = (const float4*)(Wx + (size_t)i * 8);
    float4 v0 = src[0], v1 = src[1];
    uint4 pk;
    pk.x = f2bf(v0.x) | (f2bf(v0.y) << 16);
    pk.y = f2bf(v0.z) | (f2bf(v0.w) << 16);
    pk.z = f2bf(v1.x) | (f2bf(v1.y) << 16);
    pk.w = f2bf(v1.z) | (f2bf(v1.w) << 16);
    *(uint4*)(Wxbf + (size_t)i * 8) = pk;

    __shared__ float gl[COUT];
    gl[t]       = g[b * COUT + t];
    gl[t + 256] = g[b * COUT + 256 + t];
    __syncthreads();

    float acc0 = bg[t] + bx[t], acc1 = 0.f;    // a = t, dual chain for ILP
    const float4* wr = (const float4*)(Wg + (size_t)t * COUT);
    #pragma unroll 8
    for (int co = 0; co < COUT / 4; co += 2) {
        float4 wv0 = wr[co],     gv0 = *(const float4*)&gl[co * 4];
        float4 wv1 = wr[co + 1], gv1 = *(const float4*)&gl[co * 4 + 4];
        acc0 += wv0.x * gv0.x + wv0.y * gv0.y + wv0.z * gv0.z + wv0.w * gv0.w;
        acc1 += wv1.x * gv1.x + wv1.y * gv1.y + wv1.z * gv1.z + wv1.w * gv1.w;
    }
    ggbx[b * 256 + t] = acc0 + acc1;
}

// Kernel 1: per (b, n-tile of 64): MFMA GEMM + relu + Wf reduce -> raw[b][n],
// plus partial P[b][c] = sum_n x*raw, T[b][c] = sum_n x   (fp32 atomics)
__global__ __launch_bounds__(256, 4) void attn_main(
    const float* __restrict__ x, const unsigned short* __restrict__ Wxbf,
    const float* __restrict__ ggbx, const float* __restrict__ Wf,
    const float* __restrict__ bfs,
    float* __restrict__ P, float* __restrict__ T, float* __restrict__ raw)
{
    // xT: [n=0..63][chunk 0..31][8 bf16], chunk position XOR-swizzled by n&31.
    __shared__ unsigned int xT[NT * 128];      // 32 KB (reused as reduce scratch)
    __shared__ float att_part[4][NT];
    __shared__ float raw_l[NT];

    int bid = blockIdx.x;
    int b = bid >> 6, nt = bid & 63;
    int t = threadIdx.x, w = t >> 6, lane = t & 63;
    int quad = lane >> 4, l15 = lane & 15;

    const float* xb = x + (size_t)b * CIN * HW_ + nt * NT;

    // ---- stage x tile (fp32 -> bf16, transposed into xT[n][c]) ----
    // lane: n-strip n4..n4+3, c-rows cb..cb+7 (two groups of 8 c).
    // 16 dwordx4 loads issued up-front (1 KB / wave-instr), then pack.
    {
        int sub = lane >> 4;                   // 0..3
        int n4  = (lane & 15) * 4;             // n strip base
        int cb0 = w * 64 + sub * 8;            // group 0 c-base
        int cb1 = cb0 + 32;                    // group 1 c-base
        float4_ v[16];
        #pragma unroll
        for (int j = 0; j < 8; j++)
            v[j] = *(const float4_*)(xb + (size_t)(cb0 + j) * HW_ + n4);
        #pragma unroll
        for (int j = 0; j < 8; j++)
            v[8 + j] = *(const float4_*)(xb + (size_t)(cb1 + j) * HW_ + n4);

        #pragma unroll
        for (int gq = 0; gq < 2; gq++) {
            int q = (gq ? cb1 : cb0) >> 3;
            const float4_* vg = &v[gq * 8];
            #pragma unroll
            for (int r = 0; r < 4; r++) {
                uint4 pk;
                pk.x = f2bf(vg[0][r]) | (f2bf(vg[1][r]) << 16);
                pk.y = f2bf(vg[2][r]) | (f2bf(vg[3][r]) << 16);
                pk.z = f2bf(vg[4][r]) | (f2bf(vg[5][r]) << 16);
                pk.w = f2bf(vg[6][r]) | (f2bf(vg[7][r]) << 16);
                int n = n4 + r;
                *(uint4*)&xT[n * 128 + ((q ^ (n & 31)) << 2)] = pk;
            }
        }
    }

    // per-wave a-range: a = w*64 + ai*16 + l15
    float ga[4], wfv[4];
    #pragma unroll
    for (int ai = 0; ai < 4; ai++) {
        int a = w * 64 + ai * 16 + l15;
        ga[ai]  = ggbx[b * 256 + a];
        wfv[ai] = Wf[a];
    }
    __syncthreads();

    float4_ acc[4][4];
    #pragma unroll
    for (int mi = 0; mi < 4; mi++)
        #pragma unroll
        for (int ai = 0; ai < 4; ai++)
            acc[mi][ai] = (float4_){0.f, 0.f, 0.f, 0.f};

    // ---- K loop: D[m=n_spatial][n'=a] = xT * Wx^T ----
    for (int k0 = 0; k0 < CIN; k0 += 32) {
        int qk = (k0 >> 3) + quad;
        short8 af[4];
        #pragma unroll
        for (int mi = 0; mi < 4; mi++) {
            int n = mi * 16 + l15;             // A[m=lane&15][k=quad*8+j]
            af[mi] = *(const short8*)&xT[n * 128 + ((qk ^ (n & 31)) << 2)];
        }
        short8 bfr[4];
        #pragma unroll
        for (int ai = 0; ai < 4; ai++) {
            int a = w * 64 + ai * 16 + l15;    // B[k=quad*8+j][n=lane&15]
            bfr[ai] = *(const short8*)(Wxbf + (size_t)a * 256 + k0 + quad * 8);
        }
        #pragma unroll
        for (int mi = 0; mi < 4; mi++)
            #pragma unroll
            for (int ai = 0; ai < 4; ai++)
                acc[mi][ai] = __builtin_amdgcn_mfma_f32_16x16x32_bf16(
                    af[mi], bfr[ai], acc[mi][ai], 0, 0, 0);
    }

    // ---- epilogue: relu(D + gg + bx) * Wf, reduce over a ----
    #pragma unroll
    for (int mi = 0; mi < 4; mi++) {
        float p[4] = {0.f, 0.f, 0.f, 0.f};
        #pragma unroll
        for (int ai = 0; ai < 4; ai++) {
            #pragma unroll
            for (int r = 0; r < 4; r++) {
                float vv = acc[mi][ai][r] + ga[ai];
                vv = fmaxf(vv, 0.f);
                p[r] = fmaf(vv, wfv[ai], p[r]);
            }
        }
        #pragma unroll
        for (int r = 0; r < 4; r++) {
            #pragma unroll
            for (int off = 1; off < 16; off <<= 1)
                p[r] += __shfl_xor(p[r], off, 16);
        }
        if (l15 == 0) {
            #pragma unroll
            for (int r = 0; r < 4; r++)
                att_part[w][mi * 16 + quad * 4 + r] = p[r];
        }
    }
    __syncthreads();

    if (t < NT) {
        float rv = att_part[0][t] + att_part[1][t] + att_part[2][t] + att_part[3][t] + bfs[0];
        raw[b * HW_ + nt * NT + t] = rv;
        raw_l[t] = rv;
    }
    __syncthreads();

    // ---- P/T pass: thread handles 4 consecutive c over 16 n (wave = one row/iter) ----
    float pp[4] = {0.f, 0.f, 0.f, 0.f};
    float tt[4] = {0.f, 0.f, 0.f, 0.f};
    {
        int q    = (t & 63) >> 1;              // logical chunk (8 c)
        int half = (t & 1) * 8;                // byte offset: which 4 c of the chunk
        int nb   = (t >> 6) * 16;
        #pragma unroll
        for (int i = 0; i < 16; i++) {
            int n = nb + i;
            uint2 u = *(const uint2*)((const char*)xT + n * 512 + ((q ^ (n & 31)) << 4) + half);
            float rv = raw_l[n];
            float x0 = bf2f(u.x & 0xFFFFu), x1 = bf2f(u.x >> 16);
            float x2 = bf2f(u.y & 0xFFFFu), x3 = bf2f(u.y >> 16);
            pp[0] = fmaf(x0, rv, pp[0]); tt[0] += x0;
            pp[1] = fmaf(x1, rv, pp[1]); tt[1] += x1;
            pp[2] = fmaf(x2, rv, pp[2]); tt[2] += x2;
            pp[3] = fmaf(x3, rv, pp[3]); tt[3] += x3;
        }
    }
    __syncthreads();                           // xT reads done; reuse as scratch
    {
        float* red = (float*)xT;               // [4 waves][512]: [0..255]=P, [256..511]=T
        float4_* pr = (float4_*)(red + w * 512);
        float4_* tr = (float4_*)(red + w * 512 + 256);
        pr[t & 63] = (float4_){pp[0], pp[1], pp[2], pp[3]};
        tr[t & 63] = (float4_){tt[0], tt[1], tt[2], tt[3]};
        __syncthreads();
        // c = t: sum the 4 wave partials
        float Pc = red[t] + red[512 + t] + red[1024 + t] + red[1536 + t];
        float Tc = red[256 + t] + red[768 + t] + red[1280 + t] + red[1792 + t];
        atomicAdd(&P[b * 256 + t], Pc);
        atomicAdd(&T[b * 256 + t], Tc);
    }
}

// Kernel 2: per batch: min/sum over raw, write att output and pooled out
__global__ __launch_bounds__(256) void finalize_kernel(
    const float* __restrict__ raw, const float* __restrict__ P,
    const float* __restrict__ T, float* __restrict__ out)
{
    int b = blockIdx.x, t = threadIdx.x;
    const float* r = raw + (size_t)b * HW_;
    float v[16];
    float mn = 3.4e38f, sm = 0.f;
    #pragma unroll
    for (int i = 0; i < 16; i++) {
        v[i] = r[t + 256 * i];
        mn = fminf(mn, v[i]);
        sm += v[i];
    }
    #pragma unroll
    for (int off = 1; off < 64; off <<= 1) {
        mn = fminf(mn, __shfl_xor(mn, off, 64));
        sm += __shfl_xor(sm, off, 64);
    }
    __shared__ float smn[4], ssm[4];
    int w = t >> 6;
    if ((t & 63) == 0) { smn[w] = mn; ssm[w] = sm; }
    __syncthreads();
    mn = fminf(fminf(smn[0], smn[1]), fminf(smn[2], smn[3]));
    sm = (ssm[0] + ssm[1]) + (ssm[2] + ssm[3]);
    float S = sm - 4096.f * mn;                 // sum of (raw - min)
    float inv = 1.f / S;

    float* att = out + B_ * CIN + (size_t)b * HW_;
    #pragma unroll
    for (int i = 0; i < 16; i++) att[t + 256 * i] = (v[i] - mn) * inv;

    int ic = b * 256 + t;
    out[ic] = (P[ic] - mn * T[ic]) * inv;
}

extern "C" void kernel_launch(void* const* d_in, const int* in_sizes, int n_in,
                              void* d_out, int out_size, void* d_ws, size_t ws_size,
                              hipStream_t stream)
{
    const float* x   = (const float*)d_in[0];
    const float* g   = (const float*)d_in[1];
    const float* Wg  = (const float*)d_in[2];
    const float* bg  = (const float*)d_in[3];
    const float* Wx  = (const float*)d_in[4];
    const float* bx  = (const float*)d_in[5];
    const float* Wf  = (const float*)d_in[6];
    const float* bf  = (const float*)d_in[7];
    float* out = (float*)d_out;

    char* wsb = (char*)d_ws;
    unsigned short* Wxbf = (unsigned short*)wsb;          // 128 KB
    float* ggbx = (float*)(wsb + 131072);                 // 32 KB
    float* P    = ggbx + 8192;                            // 32 KB
    float* T    = P + 8192;                               // 32 KB
    float* raw  = T + 8192;                               // 512 KB

    prep_kernel<<<32, 256, 0, stream>>>(g, Wg, bg, Wx, bx, Wxbf, ggbx, P, T);
    attn_main<<<2048, 256, 0, stream>>>(x, Wxbf, ggbx, Wf, bf, P, T, raw);
    finalize_kernel<<<32, 256, 0, stream>>>(raw, P, T, out);
}

// Round 3
// 242.817 us; speedup vs baseline: 1.0785x; 1.0359x over previous
//
#include <hip/hip_runtime.h>
#include <stdint.h>

#define B_   32
#define CIN  256
#define COUT 512
#define A_   256
#define HW_  4096
#define NT   64

typedef short  short8  __attribute__((ext_vector_type(8)));
typedef float  float4_ __attribute__((ext_vector_type(4)));

__device__ __forceinline__ unsigned f2bf(float f) {
    unsigned u = __float_as_uint(f);
    u += 0x7FFFu + ((u >> 16) & 1u);   // RNE to bf16
    return u >> 16;
}
__device__ __forceinline__ float bf2f(unsigned h) {
    return __uint_as_float(h << 16);
}

// Kernel 0 (grid 64):
//  blocks 0..31  : zero P/T, ggbx[b][a] = g@Wg.T + bg + bx
//  blocks 32..63 : WxR fragment-linear repack of Wx (bf16)
//    entry e = ((w*8+kk)*4+ai)*64 + lane  holds Wx[a=w*64+ai*16+(lane&15)]
//                                              [k=kk*32+(lane>>4)*8 .. +7]
__global__ __launch_bounds__(256) void prep_kernel(
    const float* __restrict__ g, const float* __restrict__ Wg,
    const float* __restrict__ bg, const float* __restrict__ Wx,
    const float* __restrict__ bx,
    uint4* __restrict__ WxR, float* __restrict__ ggbx,
    float* __restrict__ P, float* __restrict__ T)
{
    int t = threadIdx.x;
    if (blockIdx.x >= 32) {
        int e = (blockIdx.x - 32) * 256 + t;
        int lane = e & 63, ai = (e >> 6) & 3, kk = (e >> 8) & 7, w = e >> 11;
        int a  = w * 64 + ai * 16 + (lane & 15);
        int kb = kk * 32 + (lane >> 4) * 8;
        const float4* s = (const float4*)(Wx + (size_t)a * 256 + kb);
        float4 u0 = s[0], u1 = s[1];
        uint4 pk;
        pk.x = f2bf(u0.x) | (f2bf(u0.y) << 16);
        pk.y = f2bf(u0.z) | (f2bf(u0.w) << 16);
        pk.z = f2bf(u1.x) | (f2bf(u1.y) << 16);
        pk.w = f2bf(u1.z) | (f2bf(u1.w) << 16);
        WxR[e] = pk;
        return;
    }
    int b = blockIdx.x;
    int i = b * 256 + t;
    P[i] = 0.f; T[i] = 0.f;

    __shared__ float gl[COUT];
    gl[t]       = g[b * COUT + t];
    gl[t + 256] = g[b * COUT + 256 + t];
    __syncthreads();

    float acc0 = bg[t] + bx[t], acc1 = 0.f;    // a = t, dual chain for ILP
    const float4* wr = (const float4*)(Wg + (size_t)t * COUT);
    #pragma unroll 8
    for (int co = 0; co < COUT / 4; co += 2) {
        float4 wv0 = wr[co],     gv0 = *(const float4*)&gl[co * 4];
        float4 wv1 = wr[co + 1], gv1 = *(const float4*)&gl[co * 4 + 4];
        acc0 += wv0.x * gv0.x + wv0.y * gv0.y + wv0.z * gv0.z + wv0.w * gv0.w;
        acc1 += wv1.x * gv1.x + wv1.y * gv1.y + wv1.z * gv1.z + wv1.w * gv1.w;
    }
    ggbx[b * 256 + t] = acc0 + acc1;
}

// Kernel 1: per (b, n-tile of 64): MFMA GEMM + relu + Wf reduce -> raw[b][n],
// plus partial P[b][c] = sum_n x*raw, T[b][c] = sum_n x   (fp32 atomics)
__global__ __launch_bounds__(256, 4) void attn_main(
    const float* __restrict__ x, const char* __restrict__ WxR,
    const float* __restrict__ ggbx, const float* __restrict__ Wf,
    const float* __restrict__ bfs,
    float* __restrict__ P, float* __restrict__ T, float* __restrict__ raw)
{
    // xT: [n=0..63][chunk 0..31][8 bf16], chunk position XOR-swizzled by n&31.
    __shared__ unsigned int xT[NT * 128];      // 32 KB (reused as reduce scratch)
    __shared__ float att_part[4][NT];
    __shared__ float raw_l[NT];

    int bid = blockIdx.x;
    int b = bid >> 6, nt = bid & 63;
    int t = threadIdx.x, w = t >> 6, lane = t & 63;
    int quad = lane >> 4, l15 = lane & 15;

    const float* xb = x + (size_t)b * CIN * HW_ + nt * NT;

    // ---- stage x tile (fp32 -> bf16, transposed into xT[n][c]) ----
    {
        int sub = lane >> 4;                   // 0..3
        int n4  = (lane & 15) * 4;             // n strip base
        int cb0 = w * 64 + sub * 8;            // group 0 c-base
        int cb1 = cb0 + 32;                    // group 1 c-base
        float4_ v[16];
        #pragma unroll
        for (int j = 0; j < 8; j++)
            v[j] = *(const float4_*)(xb + (size_t)(cb0 + j) * HW_ + n4);
        #pragma unroll
        for (int j = 0; j < 8; j++)
            v[8 + j] = *(const float4_*)(xb + (size_t)(cb1 + j) * HW_ + n4);

        #pragma unroll
        for (int gq = 0; gq < 2; gq++) {
            int q = (gq ? cb1 : cb0) >> 3;
            const float4_* vg = &v[gq * 8];
            #pragma unroll
            for (int r = 0; r < 4; r++) {
                uint4 pk;
                pk.x = f2bf(vg[0][r]) | (f2bf(vg[1][r]) << 16);
                pk.y = f2bf(vg[2][r]) | (f2bf(vg[3][r]) << 16);
                pk.z = f2bf(vg[4][r]) | (f2bf(vg[5][r]) << 16);
                pk.w = f2bf(vg[6][r]) | (f2bf(vg[7][r]) << 16);
                int n = n4 + r;
                *(uint4*)&xT[n * 128 + ((q ^ (n & 31)) << 2)] = pk;
            }
        }
    }

    // per-wave a-range: a = w*64 + ai*16 + l15
    float ga[4], wfv[4];
    #pragma unroll
    for (int ai = 0; ai < 4; ai++) {
        int a = w * 64 + ai * 16 + l15;
        ga[ai]  = ggbx[b * 256 + a];
        wfv[ai] = Wf[a];
    }
    __syncthreads();

    float4_ acc[4][4];
    #pragma unroll
    for (int mi = 0; mi < 4; mi++)
        #pragma unroll
        for (int ai = 0; ai < 4; ai++)
            acc[mi][ai] = (float4_){0.f, 0.f, 0.f, 0.f};

    // ---- K loop: D[m=n_spatial][n'=a] = xT * Wx^T, distance-2 pipeline ----
    const char* wsl = WxR + w * 32768 + lane * 16;   // wave's fragment slice
    short8 afA[4], bfA[4], afB[4], bfB[4];

    auto LD = [&](short8* af, short8* bf, int k0) {
        int qk = (k0 >> 3) + quad;
        #pragma unroll
        for (int mi = 0; mi < 4; mi++) {
            int n = mi * 16 + l15;             // A[m=lane&15][k=quad*8+j]
            af[mi] = *(const short8*)&xT[n * 128 + ((qk ^ (n & 31)) << 2)];
        }
        const char* wk = wsl + (k0 >> 5) * 4096;
        #pragma unroll
        for (int ai = 0; ai < 4; ai++)         // coalesced 1 KB per instr
            bf[ai] = *(const short8*)(wk + ai * 1024);
    };
    auto MM = [&](short8* af, short8* bf) {
        #pragma unroll
        for (int mi = 0; mi < 4; mi++)
            #pragma unroll
            for (int ai = 0; ai < 4; ai++)
                acc[mi][ai] = __builtin_amdgcn_mfma_f32_16x16x32_bf16(
                    af[mi], bf[ai], acc[mi][ai], 0, 0, 0);
    };

    LD(afA, bfA, 0);   LD(afB, bfB, 32);
    MM(afA, bfA);      LD(afA, bfA, 64);
    MM(afB, bfB);      LD(afB, bfB, 96);
    MM(afA, bfA);      LD(afA, bfA, 128);
    MM(afB, bfB);      LD(afB, bfB, 160);
    MM(afA, bfA);      LD(afA, bfA, 192);
    MM(afB, bfB);      LD(afB, bfB, 224);
    MM(afA, bfA);
    MM(afB, bfB);

    // ---- epilogue: relu(D + gg + bx) * Wf, reduce over a ----
    #pragma unroll
    for (int mi = 0; mi < 4; mi++) {
        float p[4] = {0.f, 0.f, 0.f, 0.f};
        #pragma unroll
        for (int ai = 0; ai < 4; ai++) {
            #pragma unroll
            for (int r = 0; r < 4; r++) {
                float vv = acc[mi][ai][r] + ga[ai];
                vv = fmaxf(vv, 0.f);
                p[r] = fmaf(vv, wfv[ai], p[r]);
            }
        }
        #pragma unroll
        for (int r = 0; r < 4; r++) {
            #pragma unroll
            for (int off = 1; off < 16; off <<= 1)
                p[r] += __shfl_xor(p[r], off, 16);
        }
        if (l15 == 0) {
            #pragma unroll
            for (int r = 0; r < 4; r++)
                att_part[w][mi * 16 + quad * 4 + r] = p[r];
        }
    }
    __syncthreads();

    if (t < NT) {
        float rv = att_part[0][t] + att_part[1][t] + att_part[2][t] + att_part[3][t] + bfs[0];
        raw[b * HW_ + nt * NT + t] = rv;
        raw_l[t] = rv;
    }
    __syncthreads();

    // ---- P/T pass: thread handles 4 consecutive c over 16 n ----
    float pp[4] = {0.f, 0.f, 0.f, 0.f};
    float tt[4] = {0.f, 0.f, 0.f, 0.f};
    {
        int q    = (t & 63) >> 1;              // logical chunk (8 c)
        int half = (t & 1) * 8;                // which 4 c of the chunk
        int nb   = (t >> 6) * 16;
        #pragma unroll
        for (int i = 0; i < 16; i++) {
            int n = nb + i;
            uint2 u = *(const uint2*)((const char*)xT + n * 512 + ((q ^ (n & 31)) << 4) + half);
            float rv = raw_l[n];
            float x0 = bf2f(u.x & 0xFFFFu), x1 = bf2f(u.x >> 16);
            float x2 = bf2f(u.y & 0xFFFFu), x3 = bf2f(u.y >> 16);
            pp[0] = fmaf(x0, rv, pp[0]); tt[0] += x0;
            pp[1] = fmaf(x1, rv, pp[1]); tt[1] += x1;
            pp[2] = fmaf(x2, rv, pp[2]); tt[2] += x2;
            pp[3] = fmaf(x3, rv, pp[3]); tt[3] += x3;
        }
    }
    __syncthreads();                           // xT reads done; reuse as scratch
    {
        float* red = (float*)xT;               // [4 waves][512]: [0..255]=P, [256..511]=T
        float4_* pr = (float4_*)(red + w * 512);
        float4_* tr = (float4_*)(red + w * 512 + 256);
        pr[t & 63] = (float4_){pp[0], pp[1], pp[2], pp[3]};
        tr[t & 63] = (float4_){tt[0], tt[1], tt[2], tt[3]};
        __syncthreads();
        float Pc = red[t] + red[512 + t] + red[1024 + t] + red[1536 + t];
        float Tc = red[256 + t] + red[768 + t] + red[1280 + t] + red[1792 + t];
        atomicAdd(&P[b * 256 + t], Pc);
        atomicAdd(&T[b * 256 + t], Tc);
    }
}

// Kernel 2: per batch: min/sum over raw, write att output and pooled out
__global__ __launch_bounds__(256) void finalize_kernel(
    const float* __restrict__ raw, const float* __restrict__ P,
    const float* __restrict__ T, float* __restrict__ out)
{
    int b = blockIdx.x, t = threadIdx.x;
    const float* r = raw + (size_t)b * HW_;
    float v[16];
    float mn = 3.4e38f, sm = 0.f;
    #pragma unroll
    for (int i = 0; i < 16; i++) {
        v[i] = r[t + 256 * i];
        mn = fminf(mn, v[i]);
        sm += v[i];
    }
    #pragma unroll
    for (int off = 1; off < 64; off <<= 1) {
        mn = fminf(mn, __shfl_xor(mn, off, 64));
        sm += __shfl_xor(sm, off, 64);
    }
    __shared__ float smn[4], ssm[4];
    int w = t >> 6;
    if ((t & 63) == 0) { smn[w] = mn; ssm[w] = sm; }
    __syncthreads();
    mn = fminf(fminf(smn[0], smn[1]), fminf(smn[2], smn[3]));
    sm = (ssm[0] + ssm[1]) + (ssm[2] + ssm[3]);
    float S = sm - 4096.f * mn;                 // sum of (raw - min)
    float inv = 1.f / S;

    float* att = out + B_ * CIN + (size_t)b * HW_;
    #pragma unroll
    for (int i = 0; i < 16; i++) att[t + 256 * i] = (v[i] - mn) * inv;

    int ic = b * 256 + t;
    out[ic] = (P[ic] - mn * T[ic]) * inv;
}

extern "C" void kernel_launch(void* const* d_in, const int* in_sizes, int n_in,
                              void* d_out, int out_size, void* d_ws, size_t ws_size,
                              hipStream_t stream)
{
    const float* x   = (const float*)d_in[0];
    const float* g   = (const float*)d_in[1];
    const float* Wg  = (const float*)d_in[2];
    const float* bg  = (const float*)d_in[3];
    const float* Wx  = (const float*)d_in[4];
    const float* bx  = (const float*)d_in[5];
    const float* Wf  = (const float*)d_in[6];
    const float* bf  = (const float*)d_in[7];
    float* out = (float*)d_out;

    char* wsb = (char*)d_ws;
    uint4* WxR  = (uint4*)wsb;                            // 128 KB
    float* ggbx = (float*)(wsb + 131072);                 // 32 KB
    float* P    = ggbx + 8192;                            // 32 KB
    float* T    = P + 8192;                               // 32 KB
    float* raw  = T + 8192;                               // 512 KB

    prep_kernel<<<64, 256, 0, stream>>>(g, Wg, bg, Wx, bx, WxR, ggbx, P, T);
    attn_main<<<2048, 256, 0, stream>>>(x, (const char*)WxR, ggbx, Wf, bf, P, T, raw);
    finalize_kernel<<<32, 256, 0, stream>>>(raw, P, T, out);
}